// Round 1
// baseline (410.761 us; speedup 1.0000x reference)
//
#include <hip/hip_runtime.h>

// out = (((x + 2) * 3 - 5) / 4)^2 == ((3x + 1) * 0.25)^2, elementwise fp32.
// 8192*8192 = 67108864 elements, divisible by 4 -> float4 vectorized.
// Memory-bound: 512 MB total HBM traffic -> ~81 us at 6.3 TB/s achievable.

__global__ __launch_bounds__(256) void ew_kernel(const float4* __restrict__ in,
                                                 float4* __restrict__ out,
                                                 int n4) {
    int i = blockIdx.x * blockDim.x + threadIdx.x;
    if (i < n4) {
        float4 v = in[i];
        float4 r;
        // r = (3x + 1) * 0.25; out = r*r
        float a = fmaf(3.0f, v.x, 1.0f) * 0.25f;
        float b = fmaf(3.0f, v.y, 1.0f) * 0.25f;
        float c = fmaf(3.0f, v.z, 1.0f) * 0.25f;
        float d = fmaf(3.0f, v.w, 1.0f) * 0.25f;
        r.x = a * a;
        r.y = b * b;
        r.z = c * c;
        r.w = d * d;
        out[i] = r;
    }
}

// Tail kernel not needed (n % 4 == 0 for 8192^2), but guard scalar remainder
// generically so the kernel is correct for any n.
__global__ void ew_tail(const float* __restrict__ in, float* __restrict__ out,
                        int start, int n) {
    int i = start + blockIdx.x * blockDim.x + threadIdx.x;
    if (i < n) {
        float r = fmaf(3.0f, in[i], 1.0f) * 0.25f;
        out[i] = r * r;
    }
}

extern "C" void kernel_launch(void* const* d_in, const int* in_sizes, int n_in,
                              void* d_out, int out_size, void* d_ws, size_t ws_size,
                              hipStream_t stream) {
    const float* in = (const float*)d_in[0];
    float* out = (float*)d_out;
    int n = in_sizes[0];

    int n4 = n / 4;
    if (n4 > 0) {
        int threads = 256;
        int blocks = (n4 + threads - 1) / threads;
        ew_kernel<<<blocks, threads, 0, stream>>>((const float4*)in, (float4*)out, n4);
    }
    int rem = n - n4 * 4;
    if (rem > 0) {
        ew_tail<<<1, 64, 0, stream>>>(in, out, n4 * 4, n);
    }
}